// Round 8
// baseline (450.151 us; speedup 1.0000x reference)
//
#include <hip/hip_runtime.h>
#include <math.h>

#define NM 50000
#define ND 50000
#define NN 100000   // total nodes
#define DK 256      // feature dim of both sims
#define F  64       // attn feature size
#define SLOPE 0.2f

// proj tiling: 64 rows x 64 cols per block, BK=32, 4x4 micro-tile, 256 threads,
// double-buffered LDS (one barrier per K-step)
#define BR2  64
#define BK2  32
#define NB2  782    // ceil(50000/64) per half

__device__ __forceinline__ void gload_lds16(const void* g, void* l) {
    __builtin_amdgcn_global_load_lds((const __attribute__((address_space(1))) void*)g,
                                     (__attribute__((address_space(3))) void*)l, 16, 0, 0);
}

// ---------------- projection: z = [m_sim @ Wm^T ; d_sim @ Wd^T] ----------------
// R7 lesson: 8x4 tile needed 172 VGPR -> 2 waves/SIMD, and stage->barrier->compute
// exposed full staging latency each K-step. v8: 4x4 micro-tile (~90 natural VGPR,
// fits the (256,2) 128 cap like R4 did; no prefetch data regs since staging is
// global_load_lds), grid 1564, and DOUBLE-BUFFERED LDS with one barrier/step:
//   barrier (drains stage(cur), issued last iter -> had full compute to fly)
//   issue stage(step+1 -> buf^1)   [async, overlaps compute below]
//   compute(buf cur)
// Swizzle (both-sides XOR, 16B granule) carried unchanged from R6/R7 (verified;
// remaining 3.2M conflicts are the free 2-way kind, m136).
__global__ __launch_bounds__(256, 2) void proj_kernel(const float* __restrict__ m_sim,
                                                      const float* __restrict__ d_sim,
                                                      const float* __restrict__ Wm,
                                                      const float* __restrict__ Wd,
                                                      float* __restrict__ z) {
    __shared__ float As[2][BR2 * BK2];  // 2 x 8 KB, row stride 128 B
    __shared__ float Ws[2][F * BK2];    // 2 x 8 KB

    int bid  = blockIdx.x;
    bool ism = bid < NB2;
    const float* sim = ism ? m_sim : d_sim;
    const float* W   = ism ? Wm : Wd;
    int row0   = (ism ? bid : bid - NB2) * BR2;
    int nrows  = ism ? NM : ND;
    int zbase  = ism ? 0 : NM;

    int t  = threadIdx.x;     // 0..255
    int tx = t & 15;          // col group 0..15
    int ty = t >> 4;          // row group 0..15
    int w  = t >> 6;          // wave 0..3
    int l  = t & 63;          // lane
    int lrow = l >> 3;        // 0..7 (row within one stage instr's 8-row chunk)
    int sw   = ((l & 7) ^ lrow) << 4;   // swizzled 16B slot within 128B k-chunk

    // staging sources: wave w stages rows [w*16, w*16+16) of A and of W,
    // 2 gload_lds instrs each (8 rows per instr)
    const char* a_srcb[2];
    const char* w_srcb[2];
    #pragma unroll
    for (int q = 0; q < 2; ++q) {
        int r  = w * 16 + q * 8 + lrow;           // 0..63
        int gr = row0 + r; if (gr > nrows - 1) gr = nrows - 1;
        a_srcb[q] = (const char*)sim + (size_t)gr * (DK * 4) + sw;
        w_srcb[q] = (const char*)W + (size_t)r * (DK * 4) + sw;
    }

    float acc[4][4];
    #pragma unroll
    for (int i = 0; i < 4; ++i)
        #pragma unroll
        for (int j = 0; j < 4; ++j) acc[i][j] = 0.f;

    const int NK = DK / BK2;   // 8

    // prologue: stage step 0 into buf 0
    #pragma unroll
    for (int q = 0; q < 2; ++q) {
        gload_lds16(a_srcb[q], (char*)As[0] + (w * 16 + q * 8) * 128);
        gload_lds16(w_srcb[q], (char*)Ws[0] + (w * 16 + q * 8) * 128);
    }

    for (int step = 0; step < NK; ++step) {
        int cur = step & 1;
        __syncthreads();   // drains vmcnt: stage(cur) complete; buf^1 readers done

        if (step + 1 < NK) {   // issue next stage async; flies under compute below
            int koff = (step + 1) * (BK2 * 4);
            #pragma unroll
            for (int q = 0; q < 2; ++q) {
                gload_lds16(a_srcb[q] + koff, (char*)As[cur ^ 1] + (w * 16 + q * 8) * 128);
                gload_lds16(w_srcb[q] + koff, (char*)Ws[cur ^ 1] + (w * 16 + q * 8) * 128);
            }
        }

        #pragma unroll
        for (int k4 = 0; k4 < BK2 / 4; ++k4) {
            float4 a[4];
            #pragma unroll
            for (int i = 0; i < 4; ++i)
                a[i] = *(const float4*)((const char*)As[cur] + (i * 16 + ty) * 128
                                        + ((k4 ^ (ty & 7)) << 4));
            #pragma unroll
            for (int j = 0; j < 4; ++j) {
                float4 wv = *(const float4*)((const char*)Ws[cur] + (j * 16 + tx) * 128
                                             + ((k4 ^ (tx & 7)) << 4));
                #pragma unroll
                for (int i = 0; i < 4; ++i)
                    acc[i][j] += a[i].x * wv.x + a[i].y * wv.y
                               + a[i].z * wv.z + a[i].w * wv.w;
            }
        }
    }

    #pragma unroll
    for (int i = 0; i < 4; ++i) {
        int r = row0 + i * 16 + ty;
        if (r < nrows) {
            float* zr = z + (size_t)(zbase + r) * F;
            #pragma unroll
            for (int j = 0; j < 4; ++j) zr[j * 16 + tx] = acc[i][j];
        }
    }
}

// ---------------- degree histogram over dst ----------------
__global__ void hist_kernel(const int* __restrict__ dst, int* __restrict__ deg, int E) {
    int k = blockIdx.x * blockDim.x + threadIdx.x;
    if (k < E) atomicAdd(&deg[dst[k]], 1);
}

// ---------------- block-level inclusive scan (1024 elems / block) ----------------
__global__ __launch_bounds__(256) void scanA(const int* __restrict__ deg,
                                             int* __restrict__ incl,   // = offs+1
                                             int* __restrict__ bsums) {
    __shared__ int sd[256];
    int tid  = threadIdx.x;
    int base = blockIdx.x * 1024 + tid * 4;
    int v[4];
    int run = 0;
    #pragma unroll
    for (int j = 0; j < 4; ++j) {
        int i = base + j;
        int x = (i < NN) ? deg[i] : 0;
        run += x;
        v[j] = run;
    }
    sd[tid] = run;
    __syncthreads();
    for (int off = 1; off < 256; off <<= 1) {
        int t = (tid >= off) ? sd[tid - off] : 0;
        __syncthreads();
        sd[tid] += t;
        __syncthreads();
    }
    int texcl = sd[tid] - run;
    #pragma unroll
    for (int j = 0; j < 4; ++j) {
        int i = base + j;
        if (i < NN) incl[i] = texcl + v[j];
    }
    if (tid == 255) bsums[blockIdx.x] = sd[255];
}

// ---------------- scan of the block sums (exclusive, in place) ----------------
__global__ void scanB(int* __restrict__ bsums, int nb) {
    __shared__ int sd[128];
    int tid = threadIdx.x;
    int x = (tid < nb) ? bsums[tid] : 0;
    sd[tid] = x;
    __syncthreads();
    for (int off = 1; off < 128; off <<= 1) {
        int t = (tid >= off) ? sd[tid - off] : 0;
        __syncthreads();
        sd[tid] += t;
        __syncthreads();
    }
    if (tid < nb) bsums[tid] = sd[tid] - x;
}

// ---------------- finalize offsets + init scatter cursors ----------------
__global__ __launch_bounds__(256) void scanC(int* __restrict__ offs,
                                             int* __restrict__ cursor,
                                             const int* __restrict__ bsums,
                                             const int* __restrict__ deg) {
    int base = blockIdx.x * 1024 + threadIdx.x * 4;
    int add  = bsums[blockIdx.x];
    #pragma unroll
    for (int j = 0; j < 4; ++j) {
        int i = base + j;
        if (i < NN) {
            int v = offs[i + 1] + add;
            offs[i + 1] = v;
            cursor[i]   = v - deg[i];
        }
    }
    if (blockIdx.x == 0 && threadIdx.x == 0) offs[0] = 0;
}

// ---------------- scatter edges into CSR by dst ----------------
__global__ void scatter_kernel(const int* __restrict__ src, const int* __restrict__ dst,
                               int* __restrict__ cursor, int* __restrict__ csr_src, int E) {
    int k = blockIdx.x * blockDim.x + threadIdx.x;
    if (k < E) {
        int d   = dst[k];
        int pos = atomicAdd(&cursor[d], 1);
        csr_src[pos] = src[k];
    }
}

// ---------------- fused per-dst-node: scores + online softmax + aggregation + elu ----------------
// Wave per node, 4 groups of 16 lanes; each group owns one edge slot, each lane
// holds a float4 of the 64 features. 8 edges per iteration (2 per group).
__global__ __launch_bounds__(256) void gat_kernel(const float* __restrict__ z,
                                                  const int* __restrict__ offs,
                                                  const int* __restrict__ csr_src,
                                                  float* __restrict__ out) {
    int tid  = threadIdx.x;
    int node = blockIdx.x * 4 + (tid >> 6);
    int lane = tid & 63;
    int g    = lane >> 4;     // edge slot 0..3
    int i    = lane & 15;     // feature quad 0..15
    int beg = offs[node];
    int end = offs[node + 1];

    float4 zd = *(const float4*)&z[(size_t)node * F + i * 4];

    float  m = -1e30f, ssum = 0.f;
    float4 h = {0.f, 0.f, 0.f, 0.f};

    for (int j = beg; j < end; j += 8) {
        int j0 = j + g, j1 = j + 4 + g;
        bool v0 = j0 < end, v1 = j1 < end;
        int s0 = csr_src[v0 ? j0 : beg];
        int s1 = csr_src[v1 ? j1 : beg];
        float4 a = *(const float4*)&z[(size_t)s0 * F + i * 4];
        float4 b = *(const float4*)&z[(size_t)s1 * F + i * 4];
        float p0 = a.x * zd.x + a.y * zd.y + a.z * zd.z + a.w * zd.w;
        float p1 = b.x * zd.x + b.y * zd.y + b.z * zd.z + b.w * zd.w;
        #pragma unroll
        for (int o = 1; o < 16; o <<= 1) {       // 16-lane reduce, 2 chains interleaved
            p0 += __shfl_xor(p0, o, 64);
            p1 += __shfl_xor(p1, o, 64);
        }
        float e0 = (p0 > 0.f) ? p0 : SLOPE * p0;
        float e1 = (p1 > 0.f) ? p1 : SLOPE * p1;
        e0 = v0 ? e0 : -1e30f;
        e1 = v1 ? e1 : -1e30f;
        float nm = fmaxf(m, fmaxf(e0, e1));      // v_max3
        float sc = __expf(m - nm);
        float ex0 = v0 ? __expf(e0 - nm) : 0.f;
        float ex1 = v1 ? __expf(e1 - nm) : 0.f;
        ssum = ssum * sc + ex0 + ex1;
        h.x = h.x * sc + ex0 * a.x + ex1 * b.x;
        h.y = h.y * sc + ex0 * a.y + ex1 * b.y;
        h.z = h.z * sc + ex0 * a.z + ex1 * b.z;
        h.w = h.w * sc + ex0 * a.w + ex1 * b.w;
        m = nm;
    }

    // ---- merge the 4 per-group partials (offsets 16, 32) ----
    float M = fmaxf(m, __shfl_xor(m, 16, 64));
    M = fmaxf(M, __shfl_xor(M, 32, 64));
    float sc = __expf(m - M);
    float ss = ssum * sc;
    ss += __shfl_xor(ss, 16, 64);
    ss += __shfl_xor(ss, 32, 64);
    h.x *= sc; h.y *= sc; h.z *= sc; h.w *= sc;
    h.x += __shfl_xor(h.x, 16, 64); h.x += __shfl_xor(h.x, 32, 64);
    h.y += __shfl_xor(h.y, 16, 64); h.y += __shfl_xor(h.y, 32, 64);
    h.z += __shfl_xor(h.z, 16, 64); h.z += __shfl_xor(h.z, 32, 64);
    h.w += __shfl_xor(h.w, 16, 64); h.w += __shfl_xor(h.w, 32, 64);

    if (g == 0) {
        float rs = 1.0f / ss;
        bool has = end > beg;
        float4 o;
        o.x = has ? h.x * rs : 0.f;
        o.y = has ? h.y * rs : 0.f;
        o.z = has ? h.z * rs : 0.f;
        o.w = has ? h.w * rs : 0.f;
        o.x = (o.x > 0.f) ? o.x : (__expf(o.x) - 1.f);   // elu
        o.y = (o.y > 0.f) ? o.y : (__expf(o.y) - 1.f);
        o.z = (o.z > 0.f) ? o.z : (__expf(o.z) - 1.f);
        o.w = (o.w > 0.f) ? o.w : (__expf(o.w) - 1.f);
        *(float4*)&out[(size_t)node * F + i * 4] = o;
    }
}

extern "C" void kernel_launch(void* const* d_in, const int* in_sizes, int n_in,
                              void* d_out, int out_size, void* d_ws, size_t ws_size,
                              hipStream_t stream) {
    const float* m_sim = (const float*)d_in[0];
    const float* d_sim = (const float*)d_in[1];
    const float* Wm    = (const float*)d_in[2];
    const float* Wd    = (const float*)d_in[3];
    const int*   src   = (const int*)d_in[4];
    const int*   dst   = (const int*)d_in[5];
    int E = in_sizes[4];
    float* out = (float*)d_out;

    char* ws = (char*)d_ws;
    float* z      = (float*)ws; ws += (size_t)NN * F * 4;
    int*   deg    = (int*)ws;   ws += (size_t)NN * 4;
    int*   offs   = (int*)ws;   ws += (size_t)(NN + 1) * 4;
    int*   cursor = (int*)ws;   ws += (size_t)NN * 4;
    int*   bsums  = (int*)ws;   ws += 128 * 4;
    int*   csr    = (int*)ws;   ws += (size_t)E * 4;

    hipMemsetAsync(deg, 0, (size_t)NN * 4, stream);

    proj_kernel<<<NB2 * 2, 256, 0, stream>>>(m_sim, d_sim, Wm, Wd, z);
    hist_kernel<<<(E + 255) / 256, 256, 0, stream>>>(dst, deg, E);
    int nb = (NN + 1023) / 1024;   // 98
    scanA<<<nb, 256, 0, stream>>>(deg, offs + 1, bsums);
    scanB<<<1, 128, 0, stream>>>(bsums, nb);
    scanC<<<nb, 256, 0, stream>>>(offs, cursor, bsums, deg);
    scatter_kernel<<<(E + 255) / 256, 256, 0, stream>>>(src, dst, cursor, csr, E);
    gat_kernel<<<NN / 4, 256, 0, stream>>>(z, offs, csr, out);
}

// Round 9
// 372.799 us; speedup vs baseline: 1.2075x; 1.2075x over previous
//
#include <hip/hip_runtime.h>
#include <math.h>

#define NM 50000
#define ND 50000
#define NN 100000   // total nodes
#define DK 256      // feature dim of both sims
#define F  64       // attn feature size
#define SLOPE 0.2f

// proj tiling: 128 rows x 64 cols per block, BK=32, 8x4 micro-tile, 256 threads,
// double-buffered LDS (one barrier per K-step)
#define BRP  128
#define BKP  32
#define NBP  391    // ceil(50000/128)

__device__ __forceinline__ void gload_lds16(const void* g, void* l) {
    __builtin_amdgcn_global_load_lds((const __attribute__((address_space(1))) void*)g,
                                     (__attribute__((address_space(3))) void*)l, 16, 0, 0);
}

// ---------------- projection: z = [m_sim @ Wm^T ; d_sim @ Wd^T] ----------------
// R7 (this geometry, single-buffer): VGPR 172, zero spill, 135 us — latency-bound
// (stage->vmcnt(0)drain->compute serialized each K-step, VALUBusy 29%).
// R8 (4x4 + dbuf at (256,2)): cap 128 -> spill disease again (WRITE 187 MB).
// v9 = R7 geometry + R8 schedule at (256,1): cap 256, natural ~180 VGPR, no cliff.
//   barrier            (drains stage(cur) — issued one full compute phase ago)
//   issue stage(next -> buf^1)   (async, flies under compute below)
//   compute(buf cur)
// Swizzle (both-sides XOR, 16B granule): verified correct, conflicts only free 2-way.
__global__ __launch_bounds__(256, 1) void proj_kernel(const float* __restrict__ m_sim,
                                                      const float* __restrict__ d_sim,
                                                      const float* __restrict__ Wm,
                                                      const float* __restrict__ Wd,
                                                      float* __restrict__ z) {
    __shared__ float As[2][BRP * BKP];  // 2 x 16 KB, row stride 128 B
    __shared__ float Ws[2][F * BKP];    // 2 x  8 KB

    int bid  = blockIdx.x;
    bool ism = bid < NBP;
    const float* sim = ism ? m_sim : d_sim;
    const float* W   = ism ? Wm : Wd;
    int row0   = (ism ? bid : bid - NBP) * BRP;
    int nrows  = ism ? NM : ND;
    int zbase  = ism ? 0 : NM;

    int t  = threadIdx.x;     // 0..255
    int tx = t & 15;          // col group 0..15
    int ty = t >> 4;          // row group 0..15
    int w  = t >> 6;          // wave 0..3
    int l  = t & 63;          // lane
    int lrow = l >> 3;        // 0..7 (row within one stage instr's 8-row chunk)
    int sw   = ((l & 7) ^ lrow) << 4;   // swizzled 16B slot within 128B k-chunk

    // staging sources (A: 4 stage instrs/wave, W: 2/wave — same as R7)
    const char* a_srcb[4];
    #pragma unroll
    for (int q = 0; q < 4; ++q) {
        int r  = (w * 4 + q) * 8 + lrow;          // 0..127
        int gr = row0 + r; if (gr > nrows - 1) gr = nrows - 1;
        a_srcb[q] = (const char*)sim + (size_t)gr * (DK * 4) + sw;
    }
    const char* w_srcb[2];
    #pragma unroll
    for (int q = 0; q < 2; ++q) {
        int r = (w * 2 + q) * 8 + lrow;           // 0..63
        w_srcb[q] = (const char*)W + (size_t)r * (DK * 4) + sw;
    }

    float acc[8][4];
    #pragma unroll
    for (int i = 0; i < 8; ++i)
        #pragma unroll
        for (int j = 0; j < 4; ++j) acc[i][j] = 0.f;

    const int NK = DK / BKP;   // 8

    // prologue: stage step 0 into buf 0
    #pragma unroll
    for (int q = 0; q < 4; ++q)
        gload_lds16(a_srcb[q], (char*)As[0] + (w * 4 + q) * 1024);
    #pragma unroll
    for (int q = 0; q < 2; ++q)
        gload_lds16(w_srcb[q], (char*)Ws[0] + (w * 2 + q) * 1024);

    for (int step = 0; step < NK; ++step) {
        int cur = step & 1;
        __syncthreads();   // drains vmcnt: stage(cur) done; buf^1 readers done

        if (step + 1 < NK) {   // issue next stage async; flies under compute below
            int koff = (step + 1) * (BKP * 4);
            #pragma unroll
            for (int q = 0; q < 4; ++q)
                gload_lds16(a_srcb[q] + koff, (char*)As[cur ^ 1] + (w * 4 + q) * 1024);
            #pragma unroll
            for (int q = 0; q < 2; ++q)
                gload_lds16(w_srcb[q] + koff, (char*)Ws[cur ^ 1] + (w * 2 + q) * 1024);
        }

        #pragma unroll
        for (int k4 = 0; k4 < BKP / 4; ++k4) {
            float4 a[8];
            #pragma unroll
            for (int i = 0; i < 8; ++i)
                a[i] = *(const float4*)((const char*)As[cur] + (i * 16 + ty) * 128
                                        + ((k4 ^ (ty & 7)) << 4));
            #pragma unroll
            for (int j = 0; j < 4; ++j) {
                float4 wv = *(const float4*)((const char*)Ws[cur] + (j * 16 + tx) * 128
                                             + ((k4 ^ (tx & 7)) << 4));
                #pragma unroll
                for (int i = 0; i < 8; ++i)
                    acc[i][j] += a[i].x * wv.x + a[i].y * wv.y
                               + a[i].z * wv.z + a[i].w * wv.w;
            }
        }
    }

    #pragma unroll
    for (int i = 0; i < 8; ++i) {
        int r = row0 + i * 16 + ty;
        if (r < nrows) {
            float* zr = z + (size_t)(zbase + r) * F;
            #pragma unroll
            for (int j = 0; j < 4; ++j) zr[j * 16 + tx] = acc[i][j];
        }
    }
}

// ---------------- degree histogram over dst ----------------
__global__ void hist_kernel(const int* __restrict__ dst, int* __restrict__ deg, int E) {
    int k = blockIdx.x * blockDim.x + threadIdx.x;
    if (k < E) atomicAdd(&deg[dst[k]], 1);
}

// ---------------- block-level inclusive scan (1024 elems / block) ----------------
__global__ __launch_bounds__(256) void scanA(const int* __restrict__ deg,
                                             int* __restrict__ incl,   // = offs+1
                                             int* __restrict__ bsums) {
    __shared__ int sd[256];
    int tid  = threadIdx.x;
    int base = blockIdx.x * 1024 + tid * 4;
    int v[4];
    int run = 0;
    #pragma unroll
    for (int j = 0; j < 4; ++j) {
        int i = base + j;
        int x = (i < NN) ? deg[i] : 0;
        run += x;
        v[j] = run;
    }
    sd[tid] = run;
    __syncthreads();
    for (int off = 1; off < 256; off <<= 1) {
        int t = (tid >= off) ? sd[tid - off] : 0;
        __syncthreads();
        sd[tid] += t;
        __syncthreads();
    }
    int texcl = sd[tid] - run;
    #pragma unroll
    for (int j = 0; j < 4; ++j) {
        int i = base + j;
        if (i < NN) incl[i] = texcl + v[j];
    }
    if (tid == 255) bsums[blockIdx.x] = sd[255];
}

// ---------------- scan of the block sums (exclusive, in place) ----------------
__global__ void scanB(int* __restrict__ bsums, int nb) {
    __shared__ int sd[128];
    int tid = threadIdx.x;
    int x = (tid < nb) ? bsums[tid] : 0;
    sd[tid] = x;
    __syncthreads();
    for (int off = 1; off < 128; off <<= 1) {
        int t = (tid >= off) ? sd[tid - off] : 0;
        __syncthreads();
        sd[tid] += t;
        __syncthreads();
    }
    if (tid < nb) bsums[tid] = sd[tid] - x;
}

// ---------------- finalize offsets + init scatter cursors ----------------
__global__ __launch_bounds__(256) void scanC(int* __restrict__ offs,
                                             int* __restrict__ cursor,
                                             const int* __restrict__ bsums,
                                             const int* __restrict__ deg) {
    int base = blockIdx.x * 1024 + threadIdx.x * 4;
    int add  = bsums[blockIdx.x];
    #pragma unroll
    for (int j = 0; j < 4; ++j) {
        int i = base + j;
        if (i < NN) {
            int v = offs[i + 1] + add;
            offs[i + 1] = v;
            cursor[i]   = v - deg[i];
        }
    }
    if (blockIdx.x == 0 && threadIdx.x == 0) offs[0] = 0;
}

// ---------------- scatter edges into CSR by dst ----------------
__global__ void scatter_kernel(const int* __restrict__ src, const int* __restrict__ dst,
                               int* __restrict__ cursor, int* __restrict__ csr_src, int E) {
    int k = blockIdx.x * blockDim.x + threadIdx.x;
    if (k < E) {
        int d   = dst[k];
        int pos = atomicAdd(&cursor[d], 1);
        csr_src[pos] = src[k];
    }
}

// ---------------- fused per-dst-node: scores + online softmax + aggregation + elu ----------------
// Wave per node, 4 groups of 16 lanes; each group owns one edge slot, each lane
// holds a float4 of the 64 features. 8 edges per iteration (2 per group).
__global__ __launch_bounds__(256) void gat_kernel(const float* __restrict__ z,
                                                  const int* __restrict__ offs,
                                                  const int* __restrict__ csr_src,
                                                  float* __restrict__ out) {
    int tid  = threadIdx.x;
    int node = blockIdx.x * 4 + (tid >> 6);
    int lane = tid & 63;
    int g    = lane >> 4;     // edge slot 0..3
    int i    = lane & 15;     // feature quad 0..15
    int beg = offs[node];
    int end = offs[node + 1];

    float4 zd = *(const float4*)&z[(size_t)node * F + i * 4];

    float  m = -1e30f, ssum = 0.f;
    float4 h = {0.f, 0.f, 0.f, 0.f};

    for (int j = beg; j < end; j += 8) {
        int j0 = j + g, j1 = j + 4 + g;
        bool v0 = j0 < end, v1 = j1 < end;
        int s0 = csr_src[v0 ? j0 : beg];
        int s1 = csr_src[v1 ? j1 : beg];
        float4 a = *(const float4*)&z[(size_t)s0 * F + i * 4];
        float4 b = *(const float4*)&z[(size_t)s1 * F + i * 4];
        float p0 = a.x * zd.x + a.y * zd.y + a.z * zd.z + a.w * zd.w;
        float p1 = b.x * zd.x + b.y * zd.y + b.z * zd.z + b.w * zd.w;
        #pragma unroll
        for (int o = 1; o < 16; o <<= 1) {       // 16-lane reduce, 2 chains interleaved
            p0 += __shfl_xor(p0, o, 64);
            p1 += __shfl_xor(p1, o, 64);
        }
        float e0 = (p0 > 0.f) ? p0 : SLOPE * p0;
        float e1 = (p1 > 0.f) ? p1 : SLOPE * p1;
        e0 = v0 ? e0 : -1e30f;
        e1 = v1 ? e1 : -1e30f;
        float nm = fmaxf(m, fmaxf(e0, e1));      // v_max3
        float sc = __expf(m - nm);
        float ex0 = v0 ? __expf(e0 - nm) : 0.f;
        float ex1 = v1 ? __expf(e1 - nm) : 0.f;
        ssum = ssum * sc + ex0 + ex1;
        h.x = h.x * sc + ex0 * a.x + ex1 * b.x;
        h.y = h.y * sc + ex0 * a.y + ex1 * b.y;
        h.z = h.z * sc + ex0 * a.z + ex1 * b.z;
        h.w = h.w * sc + ex0 * a.w + ex1 * b.w;
        m = nm;
    }

    // ---- merge the 4 per-group partials (offsets 16, 32) ----
    float M = fmaxf(m, __shfl_xor(m, 16, 64));
    M = fmaxf(M, __shfl_xor(M, 32, 64));
    float sc = __expf(m - M);
    float ss = ssum * sc;
    ss += __shfl_xor(ss, 16, 64);
    ss += __shfl_xor(ss, 32, 64);
    h.x *= sc; h.y *= sc; h.z *= sc; h.w *= sc;
    h.x += __shfl_xor(h.x, 16, 64); h.x += __shfl_xor(h.x, 32, 64);
    h.y += __shfl_xor(h.y, 16, 64); h.y += __shfl_xor(h.y, 32, 64);
    h.z += __shfl_xor(h.z, 16, 64); h.z += __shfl_xor(h.z, 32, 64);
    h.w += __shfl_xor(h.w, 16, 64); h.w += __shfl_xor(h.w, 32, 64);

    if (g == 0) {
        float rs = 1.0f / ss;
        bool has = end > beg;
        float4 o;
        o.x = has ? h.x * rs : 0.f;
        o.y = has ? h.y * rs : 0.f;
        o.z = has ? h.z * rs : 0.f;
        o.w = has ? h.w * rs : 0.f;
        o.x = (o.x > 0.f) ? o.x : (__expf(o.x) - 1.f);   // elu
        o.y = (o.y > 0.f) ? o.y : (__expf(o.y) - 1.f);
        o.z = (o.z > 0.f) ? o.z : (__expf(o.z) - 1.f);
        o.w = (o.w > 0.f) ? o.w : (__expf(o.w) - 1.f);
        *(float4*)&out[(size_t)node * F + i * 4] = o;
    }
}

extern "C" void kernel_launch(void* const* d_in, const int* in_sizes, int n_in,
                              void* d_out, int out_size, void* d_ws, size_t ws_size,
                              hipStream_t stream) {
    const float* m_sim = (const float*)d_in[0];
    const float* d_sim = (const float*)d_in[1];
    const float* Wm    = (const float*)d_in[2];
    const float* Wd    = (const float*)d_in[3];
    const int*   src   = (const int*)d_in[4];
    const int*   dst   = (const int*)d_in[5];
    int E = in_sizes[4];
    float* out = (float*)d_out;

    char* ws = (char*)d_ws;
    float* z      = (float*)ws; ws += (size_t)NN * F * 4;
    int*   deg    = (int*)ws;   ws += (size_t)NN * 4;
    int*   offs   = (int*)ws;   ws += (size_t)(NN + 1) * 4;
    int*   cursor = (int*)ws;   ws += (size_t)NN * 4;
    int*   bsums  = (int*)ws;   ws += 128 * 4;
    int*   csr    = (int*)ws;   ws += (size_t)E * 4;

    hipMemsetAsync(deg, 0, (size_t)NN * 4, stream);

    proj_kernel<<<NBP * 2, 256, 0, stream>>>(m_sim, d_sim, Wm, Wd, z);
    hist_kernel<<<(E + 255) / 256, 256, 0, stream>>>(dst, deg, E);
    int nb = (NN + 1023) / 1024;   // 98
    scanA<<<nb, 256, 0, stream>>>(deg, offs + 1, bsums);
    scanB<<<1, 128, 0, stream>>>(bsums, nb);
    scanC<<<nb, 256, 0, stream>>>(offs, cursor, bsums, deg);
    scatter_kernel<<<(E + 255) / 256, 256, 0, stream>>>(src, dst, cursor, csr, E);
    gat_kernel<<<NN / 4, 256, 0, stream>>>(z, offs, csr, out);
}

// Round 10
// 220.546 us; speedup vs baseline: 2.0411x; 1.6903x over previous
//
#include <hip/hip_runtime.h>
#include <math.h>

#define NM 50000
#define ND 50000
#define NN 100000   // total nodes
#define DK 256      // feature dim of both sims
#define F  64       // attn feature size
#define SLOPE 0.2f

// proj tiling: 128 rows x 64 cols per block, BK=32, 8x4 micro-tile, 256 threads
#define BRP  128
#define BKP  32
#define NBP  391    // ceil(50000/128)

// edge binning: 256-node buckets
#define NBUCK 391   // ceil(100000/256)
#define BCAP  8192  // per-bucket capacity (avg fill 4092)
#define CH    4096  // edges per bin block

__device__ __forceinline__ void gload_lds16(const void* g, void* l) {
    __builtin_amdgcn_global_load_lds((const __attribute__((address_space(1))) void*)g,
                                     (__attribute__((address_space(3))) void*)l, 16, 0, 0);
}

// ---------------- projection: z = [m_sim @ Wm^T ; d_sim @ Wd^T] ----------------
// R9 verified: 8x4 micro-tile + dbuf at (256,1): no spill, staging latency hidden.
__global__ __launch_bounds__(256, 1) void proj_kernel(const float* __restrict__ m_sim,
                                                      const float* __restrict__ d_sim,
                                                      const float* __restrict__ Wm,
                                                      const float* __restrict__ Wd,
                                                      float* __restrict__ z) {
    __shared__ float As[2][BRP * BKP];  // 2 x 16 KB, row stride 128 B
    __shared__ float Ws[2][F * BKP];    // 2 x  8 KB

    int bid  = blockIdx.x;
    bool ism = bid < NBP;
    const float* sim = ism ? m_sim : d_sim;
    const float* W   = ism ? Wm : Wd;
    int row0   = (ism ? bid : bid - NBP) * BRP;
    int nrows  = ism ? NM : ND;
    int zbase  = ism ? 0 : NM;

    int t  = threadIdx.x;
    int tx = t & 15;
    int ty = t >> 4;
    int w  = t >> 6;
    int l  = t & 63;
    int lrow = l >> 3;
    int sw   = ((l & 7) ^ lrow) << 4;

    const char* a_srcb[4];
    #pragma unroll
    for (int q = 0; q < 4; ++q) {
        int r  = (w * 4 + q) * 8 + lrow;
        int gr = row0 + r; if (gr > nrows - 1) gr = nrows - 1;
        a_srcb[q] = (const char*)sim + (size_t)gr * (DK * 4) + sw;
    }
    const char* w_srcb[2];
    #pragma unroll
    for (int q = 0; q < 2; ++q) {
        int r = (w * 2 + q) * 8 + lrow;
        w_srcb[q] = (const char*)W + (size_t)r * (DK * 4) + sw;
    }

    float acc[8][4];
    #pragma unroll
    for (int i = 0; i < 8; ++i)
        #pragma unroll
        for (int j = 0; j < 4; ++j) acc[i][j] = 0.f;

    const int NK = DK / BKP;   // 8

    #pragma unroll
    for (int q = 0; q < 4; ++q)
        gload_lds16(a_srcb[q], (char*)As[0] + (w * 4 + q) * 1024);
    #pragma unroll
    for (int q = 0; q < 2; ++q)
        gload_lds16(w_srcb[q], (char*)Ws[0] + (w * 2 + q) * 1024);

    for (int step = 0; step < NK; ++step) {
        int cur = step & 1;
        __syncthreads();

        if (step + 1 < NK) {
            int koff = (step + 1) * (BKP * 4);
            #pragma unroll
            for (int q = 0; q < 4; ++q)
                gload_lds16(a_srcb[q] + koff, (char*)As[cur ^ 1] + (w * 4 + q) * 1024);
            #pragma unroll
            for (int q = 0; q < 2; ++q)
                gload_lds16(w_srcb[q] + koff, (char*)Ws[cur ^ 1] + (w * 2 + q) * 1024);
        }

        #pragma unroll
        for (int k4 = 0; k4 < BKP / 4; ++k4) {
            float4 a[8];
            #pragma unroll
            for (int i = 0; i < 8; ++i)
                a[i] = *(const float4*)((const char*)As[cur] + (i * 16 + ty) * 128
                                        + ((k4 ^ (ty & 7)) << 4));
            #pragma unroll
            for (int j = 0; j < 4; ++j) {
                float4 wv = *(const float4*)((const char*)Ws[cur] + (j * 16 + tx) * 128
                                             + ((k4 ^ (tx & 7)) << 4));
                #pragma unroll
                for (int i = 0; i < 8; ++i)
                    acc[i][j] += a[i].x * wv.x + a[i].y * wv.y
                               + a[i].z * wv.z + a[i].w * wv.w;
            }
        }
    }

    #pragma unroll
    for (int i = 0; i < 8; ++i) {
        int r = row0 + i * 16 + ty;
        if (r < nrows) {
            float* zr = z + (size_t)(zbase + r) * F;
            #pragma unroll
            for (int j = 0; j < 4; ++j) zr[j * 16 + tx] = acc[i][j];
        }
    }
}

// ---------------- stage 1: bin edges into 256-node buckets (LDS-grouped) ----------------
// R9 diagnosis: direct scatter had 16x write amplification (105 MB for 6.4 MB csr)
// from 4B random writes bouncing csr lines across 8 non-coherent XCD L2s.
// Fix: group each 4096-edge chunk by bucket in LDS, append grouped runs (~42B avg)
// to per-bucket global regions. Write amplification ~1.3x.
__global__ __launch_bounds__(512) void bin_kernel(const int* __restrict__ src,
                                                  const int* __restrict__ dst,
                                                  int* __restrict__ srcb_g,
                                                  int* __restrict__ dstb_g,
                                                  int* __restrict__ bcur,   // [512] zeroed
                                                  int E) {
    __shared__ int cnt[512], sc[512], lcur[512], gbase[512];
    __shared__ int srcb_l[CH], dstb_l[CH];

    int t    = threadIdx.x;
    int base = blockIdx.x * CH;
    int chunkN = E - base; if (chunkN > CH) chunkN = CH;

    cnt[t] = 0;
    __syncthreads();

    int ss[8], ds[8];
    #pragma unroll
    for (int e = 0; e < 8; ++e) {
        int k = base + e * 512 + t;
        if (e * 512 + t < chunkN) {
            ds[e] = dst[k];
            ss[e] = src[k];
            atomicAdd(&cnt[ds[e] >> 8], 1);
        }
    }
    __syncthreads();

    // inclusive scan of cnt -> sc; lexcl = sc - cnt
    sc[t] = cnt[t];
    __syncthreads();
    for (int off = 1; off < 512; off <<= 1) {
        int v = (t >= off) ? sc[t - off] : 0;
        __syncthreads();
        sc[t] += v;
        __syncthreads();
    }
    int lexcl_t = sc[t] - cnt[t];
    sc[t] = lexcl_t;          // sc now holds exclusive offsets
    lcur[t] = lexcl_t;
    gbase[t] = atomicAdd(&bcur[t], cnt[t]);   // reserve global space per bucket
    __syncthreads();

    #pragma unroll
    for (int e = 0; e < 8; ++e) {
        if (e * 512 + t < chunkN) {
            int b = ds[e] >> 8;
            int p = atomicAdd(&lcur[b], 1);
            srcb_l[p] = ss[e];
            dstb_l[p] = ds[e];
        }
    }
    __syncthreads();

    for (int idx = t; idx < chunkN; idx += 512) {
        int d = dstb_l[idx];
        int b = d >> 8;
        int g = b * BCAP + gbase[b] + (idx - sc[b]);
        srcb_g[g] = srcb_l[idx];
        dstb_g[g] = d;
    }
}

// ---------------- stage 2a: per-node degree from binned dst (LDS atomics) ----------------
__global__ __launch_bounds__(256) void deg_kernel(const int* __restrict__ dstb_g,
                                                  const int* __restrict__ bcur,
                                                  int* __restrict__ deg) {
    __shared__ int dcnt[256];
    int b = blockIdx.x;
    int t = threadIdx.x;
    int node0 = b << 8;
    int nn = NN - node0; if (nn > 256) nn = 256;
    dcnt[t] = 0;
    __syncthreads();
    int nbe = bcur[b];
    const int* dp = dstb_g + (size_t)b * BCAP;
    for (int i = t; i < nbe; i += 256)
        atomicAdd(&dcnt[dp[i] & 255], 1);
    __syncthreads();
    if (t < nn) deg[node0 + t] = dcnt[t];
}

// ---------------- block-level inclusive scan (1024 elems / block) ----------------
__global__ __launch_bounds__(256) void scanA(const int* __restrict__ deg,
                                             int* __restrict__ incl,   // = offs+1
                                             int* __restrict__ bsums) {
    __shared__ int sd[256];
    int tid  = threadIdx.x;
    int base = blockIdx.x * 1024 + tid * 4;
    int v[4];
    int run = 0;
    #pragma unroll
    for (int j = 0; j < 4; ++j) {
        int i = base + j;
        int x = (i < NN) ? deg[i] : 0;
        run += x;
        v[j] = run;
    }
    sd[tid] = run;
    __syncthreads();
    for (int off = 1; off < 256; off <<= 1) {
        int t = (tid >= off) ? sd[tid - off] : 0;
        __syncthreads();
        sd[tid] += t;
        __syncthreads();
    }
    int texcl = sd[tid] - run;
    #pragma unroll
    for (int j = 0; j < 4; ++j) {
        int i = base + j;
        if (i < NN) incl[i] = texcl + v[j];
    }
    if (tid == 255) bsums[blockIdx.x] = sd[255];
}

// ---------------- scan of the block sums (exclusive, in place) ----------------
__global__ void scanB(int* __restrict__ bsums, int nb) {
    __shared__ int sd[128];
    int tid = threadIdx.x;
    int x = (tid < nb) ? bsums[tid] : 0;
    sd[tid] = x;
    __syncthreads();
    for (int off = 1; off < 128; off <<= 1) {
        int t = (tid >= off) ? sd[tid - off] : 0;
        __syncthreads();
        sd[tid] += t;
        __syncthreads();
    }
    if (tid < nb) bsums[tid] = sd[tid] - x;
}

// ---------------- finalize offsets ----------------
__global__ __launch_bounds__(256) void scanC(int* __restrict__ offs,
                                             const int* __restrict__ bsums) {
    int base = blockIdx.x * 1024 + threadIdx.x * 4;
    int add  = bsums[blockIdx.x];
    #pragma unroll
    for (int j = 0; j < 4; ++j) {
        int i = base + j;
        if (i < NN) offs[i + 1] += add;
    }
    if (blockIdx.x == 0 && threadIdx.x == 0) offs[0] = 0;
}

// ---------------- stage 2b: XCD-local scatter into CSR ----------------
// One block per bucket: csr region (~16 KB) written by exactly one block ->
// lines written back once. Cursors in LDS.
__global__ __launch_bounds__(256) void scatter2(const int* __restrict__ srcb_g,
                                                const int* __restrict__ dstb_g,
                                                const int* __restrict__ bcur,
                                                const int* __restrict__ offs,
                                                int* __restrict__ csr) {
    __shared__ int lcur[256];
    int b = blockIdx.x;
    int t = threadIdx.x;
    int node0 = b << 8;
    int nn = NN - node0; if (nn > 256) nn = 256;
    if (t < nn) lcur[t] = offs[node0 + t];
    __syncthreads();
    int nbe = bcur[b];
    const int* sp = srcb_g + (size_t)b * BCAP;
    const int* dp = dstb_g + (size_t)b * BCAP;
    for (int i = t; i < nbe; i += 256) {
        int d = dp[i];
        int s = sp[i];
        int pos = atomicAdd(&lcur[d & 255], 1);
        csr[pos] = s;
    }
}

// ---------------- fused per-dst-node: scores + online softmax + aggregation + elu ----------------
__global__ __launch_bounds__(256) void gat_kernel(const float* __restrict__ z,
                                                  const int* __restrict__ offs,
                                                  const int* __restrict__ csr_src,
                                                  float* __restrict__ out) {
    int tid  = threadIdx.x;
    int node = blockIdx.x * 4 + (tid >> 6);
    int lane = tid & 63;
    int g    = lane >> 4;     // edge slot 0..3
    int i    = lane & 15;     // feature quad 0..15
    int beg = offs[node];
    int end = offs[node + 1];

    float4 zd = *(const float4*)&z[(size_t)node * F + i * 4];

    float  m = -1e30f, ssum = 0.f;
    float4 h = {0.f, 0.f, 0.f, 0.f};

    for (int j = beg; j < end; j += 8) {
        int j0 = j + g, j1 = j + 4 + g;
        bool v0 = j0 < end, v1 = j1 < end;
        int s0 = csr_src[v0 ? j0 : beg];
        int s1 = csr_src[v1 ? j1 : beg];
        float4 a = *(const float4*)&z[(size_t)s0 * F + i * 4];
        float4 b = *(const float4*)&z[(size_t)s1 * F + i * 4];
        float p0 = a.x * zd.x + a.y * zd.y + a.z * zd.z + a.w * zd.w;
        float p1 = b.x * zd.x + b.y * zd.y + b.z * zd.z + b.w * zd.w;
        #pragma unroll
        for (int o = 1; o < 16; o <<= 1) {
            p0 += __shfl_xor(p0, o, 64);
            p1 += __shfl_xor(p1, o, 64);
        }
        float e0 = (p0 > 0.f) ? p0 : SLOPE * p0;
        float e1 = (p1 > 0.f) ? p1 : SLOPE * p1;
        e0 = v0 ? e0 : -1e30f;
        e1 = v1 ? e1 : -1e30f;
        float nm = fmaxf(m, fmaxf(e0, e1));
        float sc = __expf(m - nm);
        float ex0 = v0 ? __expf(e0 - nm) : 0.f;
        float ex1 = v1 ? __expf(e1 - nm) : 0.f;
        ssum = ssum * sc + ex0 + ex1;
        h.x = h.x * sc + ex0 * a.x + ex1 * b.x;
        h.y = h.y * sc + ex0 * a.y + ex1 * b.y;
        h.z = h.z * sc + ex0 * a.z + ex1 * b.z;
        h.w = h.w * sc + ex0 * a.w + ex1 * b.w;
        m = nm;
    }

    float M = fmaxf(m, __shfl_xor(m, 16, 64));
    M = fmaxf(M, __shfl_xor(M, 32, 64));
    float sc = __expf(m - M);
    float ss = ssum * sc;
    ss += __shfl_xor(ss, 16, 64);
    ss += __shfl_xor(ss, 32, 64);
    h.x *= sc; h.y *= sc; h.z *= sc; h.w *= sc;
    h.x += __shfl_xor(h.x, 16, 64); h.x += __shfl_xor(h.x, 32, 64);
    h.y += __shfl_xor(h.y, 16, 64); h.y += __shfl_xor(h.y, 32, 64);
    h.z += __shfl_xor(h.z, 16, 64); h.z += __shfl_xor(h.z, 32, 64);
    h.w += __shfl_xor(h.w, 16, 64); h.w += __shfl_xor(h.w, 32, 64);

    if (g == 0) {
        float rs = 1.0f / ss;
        bool has = end > beg;
        float4 o;
        o.x = has ? h.x * rs : 0.f;
        o.y = has ? h.y * rs : 0.f;
        o.z = has ? h.z * rs : 0.f;
        o.w = has ? h.w * rs : 0.f;
        o.x = (o.x > 0.f) ? o.x : (__expf(o.x) - 1.f);
        o.y = (o.y > 0.f) ? o.y : (__expf(o.y) - 1.f);
        o.z = (o.z > 0.f) ? o.z : (__expf(o.z) - 1.f);
        o.w = (o.w > 0.f) ? o.w : (__expf(o.w) - 1.f);
        *(float4*)&out[(size_t)node * F + i * 4] = o;
    }
}

extern "C" void kernel_launch(void* const* d_in, const int* in_sizes, int n_in,
                              void* d_out, int out_size, void* d_ws, size_t ws_size,
                              hipStream_t stream) {
    const float* m_sim = (const float*)d_in[0];
    const float* d_sim = (const float*)d_in[1];
    const float* Wm    = (const float*)d_in[2];
    const float* Wd    = (const float*)d_in[3];
    const int*   src   = (const int*)d_in[4];
    const int*   dst   = (const int*)d_in[5];
    int E = in_sizes[4];
    float* out = (float*)d_out;

    char* ws = (char*)d_ws;
    float* z      = (float*)ws; ws += (size_t)NN * F * 4;
    int*   deg    = (int*)ws;   ws += (size_t)NN * 4;
    int*   offs   = (int*)ws;   ws += (size_t)(NN + 1) * 4;
    int*   bsums  = (int*)ws;   ws += 128 * 4;
    int*   bcur   = (int*)ws;   ws += 512 * 4;
    int*   csr    = (int*)ws;   ws += (size_t)E * 4;
    int*   srcb_g = (int*)ws;   ws += (size_t)NBUCK * BCAP * 4;
    int*   dstb_g = (int*)ws;   ws += (size_t)NBUCK * BCAP * 4;

    hipMemsetAsync(bcur, 0, 512 * 4, stream);

    int nchunks = (E + CH - 1) / CH;
    bin_kernel<<<nchunks, 512, 0, stream>>>(src, dst, srcb_g, dstb_g, bcur, E);
    proj_kernel<<<NBP * 2, 256, 0, stream>>>(m_sim, d_sim, Wm, Wd, z);
    deg_kernel<<<NBUCK, 256, 0, stream>>>(dstb_g, bcur, deg);
    int nb = (NN + 1023) / 1024;   // 98
    scanA<<<nb, 256, 0, stream>>>(deg, offs + 1, bsums);
    scanB<<<1, 128, 0, stream>>>(bsums, nb);
    scanC<<<nb, 256, 0, stream>>>(offs, bsums);
    scatter2<<<NBUCK, 256, 0, stream>>>(srcb_g, dstb_g, bcur, offs, csr);
    gat_kernel<<<NN / 4, 256, 0, stream>>>(z, offs, csr, out);
}

// Round 11
// 191.671 us; speedup vs baseline: 2.3486x; 1.1506x over previous
//
#include <hip/hip_runtime.h>
#include <math.h>

#define NM 50000
#define ND 50000
#define NN 100000   // total nodes
#define DK 256      // feature dim of both sims
#define F  64       // attn feature size
#define SLOPE 0.2f

// proj tiling: 128 rows x 64 cols per block, BK=16, 8x4 micro-tile, 256 threads,
// double-buffered LDS (24 KB), unroll-1 step loop, VGPR cap 128 -> 16 waves/CU
#define BRP  128
#define BKP  16
#define NBP  391    // ceil(50000/128)

// edge binning: 256-node buckets
#define NBUCK 391   // ceil(100000/256)
#define BCAP  8192  // per-bucket capacity (avg fill 4092)
#define CH    4096  // edges per bin block

__device__ __forceinline__ void gload_lds16(const void* g, void* l) {
    __builtin_amdgcn_global_load_lds((const __attribute__((address_space(1))) void*)g,
                                     (__attribute__((address_space(3))) void*)l, 16, 0, 0);
}

// ---------------- projection: z = [m_sim @ Wm^T ; d_sim @ Wd^T] ----------------
// R10: 123us at 12 waves/CU (VGPR 132 -> 3 waves/SIMD; LDS 48KB -> 3 blocks/CU),
// VALUBusy 30% = latency-bound ~2.7x above the 46us LDS floor.
// v10: BK=16 (LDS 24KB -> 4 blocks/CU), #pragma unroll 1 on step loop (R7/R8
// forensics: full unroll of the compile-time-constant NK loop inflated live
// ranges to 172 VGPR), int offsets instead of pointer arrays, cap (256,2).
// -> 16 waves/CU. Swizzle for 64B rows: slot' = slot ^ ((row>>1)&3); w-reads
// spread 16 rows over 8 bank-quads x2 (free 2-way), a-reads <=2-way.
__global__ __launch_bounds__(256, 2) void proj_kernel(const float* __restrict__ m_sim,
                                                      const float* __restrict__ d_sim,
                                                      const float* __restrict__ Wm,
                                                      const float* __restrict__ Wd,
                                                      float* __restrict__ z) {
    __shared__ float As[2][BRP * BKP];  // 2 x 8 KB, row stride 64 B
    __shared__ float Ws[2][F * BKP];    // 2 x 4 KB

    int bid  = blockIdx.x;
    bool ism = bid < NBP;
    const float* sim = ism ? m_sim : d_sim;
    const float* W   = ism ? Wm : Wd;
    int row0   = (ism ? bid : bid - NBP) * BRP;
    int nrows  = ism ? NM : ND;
    int zbase  = ism ? 0 : NM;

    int t  = threadIdx.x;     // 0..255
    int tx = t & 15;          // col group 0..15
    int ty = t >> 4;          // row group 0..15
    int w  = t >> 6;          // wave 0..3
    int l  = t & 63;          // lane
    int lrow  = l >> 2;       // 0..15 (row within one stage instr's 16-row chunk)
    int sw    = ((l & 3) ^ ((l >> 3) & 3)) << 4;   // swizzled 16B slot in 64B row

    // staging source offsets (bytes from sim/W base). A: 2 instrs/wave, W: 1/wave.
    int aoff[2];
    #pragma unroll
    for (int q = 0; q < 2; ++q) {
        int r  = (w * 2 + q) * 16 + lrow;          // 0..127
        int gr = row0 + r; if (gr > nrows - 1) gr = nrows - 1;
        aoff[q] = gr * (DK * 4) + sw;
    }
    int woff = (w * 16 + lrow) * (DK * 4) + sw;    // rows 0..63

    // read-side swizzle keys
    int akey = (ty >> 1) & 3;
    int wkey = (tx >> 1) & 3;

    float acc[8][4];
    #pragma unroll
    for (int i = 0; i < 8; ++i)
        #pragma unroll
        for (int j = 0; j < 4; ++j) acc[i][j] = 0.f;

    const int NK = DK / BKP;   // 16

    // prologue: stage step 0 into buf 0
    #pragma unroll
    for (int q = 0; q < 2; ++q)
        gload_lds16((const char*)sim + (size_t)aoff[q], (char*)As[0] + (w * 2 + q) * 1024);
    gload_lds16((const char*)W + (size_t)woff, (char*)Ws[0] + w * 1024);

    #pragma unroll 1
    for (int step = 0; step < NK; ++step) {
        int cur = step & 1;
        __syncthreads();   // drains vmcnt: stage(cur) done; buf^1 readers done

        if (step + 1 < NK) {   // issue next stage async; flies under compute below
            int koff = (step + 1) * (BKP * 4);   // 64 B per K-step
            #pragma unroll
            for (int q = 0; q < 2; ++q)
                gload_lds16((const char*)sim + (size_t)(aoff[q] + koff),
                            (char*)As[cur ^ 1] + (w * 2 + q) * 1024);
            gload_lds16((const char*)W + (size_t)(woff + koff),
                        (char*)Ws[cur ^ 1] + w * 1024);
        }

        #pragma unroll
        for (int k4 = 0; k4 < BKP / 4; ++k4) {
            float4 a[8];
            #pragma unroll
            for (int i = 0; i < 8; ++i)
                a[i] = *(const float4*)((const char*)As[cur] + (i * 16 + ty) * 64
                                        + ((k4 ^ akey) << 4));
            #pragma unroll
            for (int j = 0; j < 4; ++j) {
                float4 wv = *(const float4*)((const char*)Ws[cur] + (j * 16 + tx) * 64
                                             + ((k4 ^ wkey) << 4));
                #pragma unroll
                for (int i = 0; i < 8; ++i)
                    acc[i][j] += a[i].x * wv.x + a[i].y * wv.y
                               + a[i].z * wv.z + a[i].w * wv.w;
            }
        }
    }

    #pragma unroll
    for (int i = 0; i < 8; ++i) {
        int r = row0 + i * 16 + ty;
        if (r < nrows) {
            float* zr = z + (size_t)(zbase + r) * F;
            #pragma unroll
            for (int j = 0; j < 4; ++j) zr[j * 16 + tx] = acc[i][j];
        }
    }
}

// ---------------- stage 1: bin edges into 256-node buckets (LDS-grouped) ----------------
__global__ __launch_bounds__(512) void bin_kernel(const int* __restrict__ src,
                                                  const int* __restrict__ dst,
                                                  int* __restrict__ srcb_g,
                                                  int* __restrict__ dstb_g,
                                                  int* __restrict__ bcur,   // [512] zeroed
                                                  int E) {
    __shared__ int cnt[512], sc[512], lcur[512], gbase[512];
    __shared__ int srcb_l[CH], dstb_l[CH];

    int t    = threadIdx.x;
    int base = blockIdx.x * CH;
    int chunkN = E - base; if (chunkN > CH) chunkN = CH;

    cnt[t] = 0;
    __syncthreads();

    int ss[8], ds[8];
    #pragma unroll
    for (int e = 0; e < 8; ++e) {
        int k = base + e * 512 + t;
        if (e * 512 + t < chunkN) {
            ds[e] = dst[k];
            ss[e] = src[k];
            atomicAdd(&cnt[ds[e] >> 8], 1);
        }
    }
    __syncthreads();

    sc[t] = cnt[t];
    __syncthreads();
    for (int off = 1; off < 512; off <<= 1) {
        int v = (t >= off) ? sc[t - off] : 0;
        __syncthreads();
        sc[t] += v;
        __syncthreads();
    }
    int lexcl_t = sc[t] - cnt[t];
    sc[t] = lexcl_t;
    lcur[t] = lexcl_t;
    gbase[t] = atomicAdd(&bcur[t], cnt[t]);
    __syncthreads();

    #pragma unroll
    for (int e = 0; e < 8; ++e) {
        if (e * 512 + t < chunkN) {
            int b = ds[e] >> 8;
            int p = atomicAdd(&lcur[b], 1);
            srcb_l[p] = ss[e];
            dstb_l[p] = ds[e];
        }
    }
    __syncthreads();

    for (int idx = t; idx < chunkN; idx += 512) {
        int d = dstb_l[idx];
        int b = d >> 8;
        int g = b * BCAP + gbase[b] + (idx - sc[b]);
        srcb_g[g] = srcb_l[idx];
        dstb_g[g] = d;
    }
}

// ---------------- stage 2a: per-node degree from binned dst (LDS atomics) ----------------
__global__ __launch_bounds__(256) void deg_kernel(const int* __restrict__ dstb_g,
                                                  const int* __restrict__ bcur,
                                                  int* __restrict__ deg) {
    __shared__ int dcnt[256];
    int b = blockIdx.x;
    int t = threadIdx.x;
    int node0 = b << 8;
    int nn = NN - node0; if (nn > 256) nn = 256;
    dcnt[t] = 0;
    __syncthreads();
    int nbe = bcur[b];
    const int* dp = dstb_g + (size_t)b * BCAP;
    for (int i = t; i < nbe; i += 256)
        atomicAdd(&dcnt[dp[i] & 255], 1);
    __syncthreads();
    if (t < nn) deg[node0 + t] = dcnt[t];
}

// ---------------- block-level inclusive scan (1024 elems / block) ----------------
__global__ __launch_bounds__(256) void scanA(const int* __restrict__ deg,
                                             int* __restrict__ incl,   // = offs+1
                                             int* __restrict__ bsums) {
    __shared__ int sd[256];
    int tid  = threadIdx.x;
    int base = blockIdx.x * 1024 + tid * 4;
    int v[4];
    int run = 0;
    #pragma unroll
    for (int j = 0; j < 4; ++j) {
        int i = base + j;
        int x = (i < NN) ? deg[i] : 0;
        run += x;
        v[j] = run;
    }
    sd[tid] = run;
    __syncthreads();
    for (int off = 1; off < 256; off <<= 1) {
        int t = (tid >= off) ? sd[tid - off] : 0;
        __syncthreads();
        sd[tid] += t;
        __syncthreads();
    }
    int texcl = sd[tid] - run;
    #pragma unroll
    for (int j = 0; j < 4; ++j) {
        int i = base + j;
        if (i < NN) incl[i] = texcl + v[j];
    }
    if (tid == 255) bsums[blockIdx.x] = sd[255];
}

// ---------------- scan of the block sums (exclusive, in place) ----------------
__global__ void scanB(int* __restrict__ bsums, int nb) {
    __shared__ int sd[128];
    int tid = threadIdx.x;
    int x = (tid < nb) ? bsums[tid] : 0;
    sd[tid] = x;
    __syncthreads();
    for (int off = 1; off < 128; off <<= 1) {
        int t = (tid >= off) ? sd[tid - off] : 0;
        __syncthreads();
        sd[tid] += t;
        __syncthreads();
    }
    if (tid < nb) bsums[tid] = sd[tid] - x;
}

// ---------------- finalize offsets ----------------
__global__ __launch_bounds__(256) void scanC(int* __restrict__ offs,
                                             const int* __restrict__ bsums) {
    int base = blockIdx.x * 1024 + threadIdx.x * 4;
    int add  = bsums[blockIdx.x];
    #pragma unroll
    for (int j = 0; j < 4; ++j) {
        int i = base + j;
        if (i < NN) offs[i + 1] += add;
    }
    if (blockIdx.x == 0 && threadIdx.x == 0) offs[0] = 0;
}

// ---------------- stage 2b: XCD-local scatter into CSR ----------------
__global__ __launch_bounds__(256) void scatter2(const int* __restrict__ srcb_g,
                                                const int* __restrict__ dstb_g,
                                                const int* __restrict__ bcur,
                                                const int* __restrict__ offs,
                                                int* __restrict__ csr) {
    __shared__ int lcur[256];
    int b = blockIdx.x;
    int t = threadIdx.x;
    int node0 = b << 8;
    int nn = NN - node0; if (nn > 256) nn = 256;
    if (t < nn) lcur[t] = offs[node0 + t];
    __syncthreads();
    int nbe = bcur[b];
    const int* sp = srcb_g + (size_t)b * BCAP;
    const int* dp = dstb_g + (size_t)b * BCAP;
    for (int i = t; i < nbe; i += 256) {
        int d = dp[i];
        int s = sp[i];
        int pos = atomicAdd(&lcur[d & 255], 1);
        csr[pos] = s;
    }
}

// ---------------- fused per-dst-node: scores + online softmax + aggregation + elu ----------------
__global__ __launch_bounds__(256) void gat_kernel(const float* __restrict__ z,
                                                  const int* __restrict__ offs,
                                                  const int* __restrict__ csr_src,
                                                  float* __restrict__ out) {
    int tid  = threadIdx.x;
    int node = blockIdx.x * 4 + (tid >> 6);
    int lane = tid & 63;
    int g    = lane >> 4;     // edge slot 0..3
    int i    = lane & 15;     // feature quad 0..15
    int beg = offs[node];
    int end = offs[node + 1];

    float4 zd = *(const float4*)&z[(size_t)node * F + i * 4];

    float  m = -1e30f, ssum = 0.f;
    float4 h = {0.f, 0.f, 0.f, 0.f};

    for (int j = beg; j < end; j += 8) {
        int j0 = j + g, j1 = j + 4 + g;
        bool v0 = j0 < end, v1 = j1 < end;
        int s0 = csr_src[v0 ? j0 : beg];
        int s1 = csr_src[v1 ? j1 : beg];
        float4 a = *(const float4*)&z[(size_t)s0 * F + i * 4];
        float4 b = *(const float4*)&z[(size_t)s1 * F + i * 4];
        float p0 = a.x * zd.x + a.y * zd.y + a.z * zd.z + a.w * zd.w;
        float p1 = b.x * zd.x + b.y * zd.y + b.z * zd.z + b.w * zd.w;
        #pragma unroll
        for (int o = 1; o < 16; o <<= 1) {
            p0 += __shfl_xor(p0, o, 64);
            p1 += __shfl_xor(p1, o, 64);
        }
        float e0 = (p0 > 0.f) ? p0 : SLOPE * p0;
        float e1 = (p1 > 0.f) ? p1 : SLOPE * p1;
        e0 = v0 ? e0 : -1e30f;
        e1 = v1 ? e1 : -1e30f;
        float nm = fmaxf(m, fmaxf(e0, e1));
        float sc = __expf(m - nm);
        float ex0 = v0 ? __expf(e0 - nm) : 0.f;
        float ex1 = v1 ? __expf(e1 - nm) : 0.f;
        ssum = ssum * sc + ex0 + ex1;
        h.x = h.x * sc + ex0 * a.x + ex1 * b.x;
        h.y = h.y * sc + ex0 * a.y + ex1 * b.y;
        h.z = h.z * sc + ex0 * a.z + ex1 * b.z;
        h.w = h.w * sc + ex0 * a.w + ex1 * b.w;
        m = nm;
    }

    float M = fmaxf(m, __shfl_xor(m, 16, 64));
    M = fmaxf(M, __shfl_xor(M, 32, 64));
    float sc = __expf(m - M);
    float ss = ssum * sc;
    ss += __shfl_xor(ss, 16, 64);
    ss += __shfl_xor(ss, 32, 64);
    h.x *= sc; h.y *= sc; h.z *= sc; h.w *= sc;
    h.x += __shfl_xor(h.x, 16, 64); h.x += __shfl_xor(h.x, 32, 64);
    h.y += __shfl_xor(h.y, 16, 64); h.y += __shfl_xor(h.y, 32, 64);
    h.z += __shfl_xor(h.z, 16, 64); h.z += __shfl_xor(h.z, 32, 64);
    h.w += __shfl_xor(h.w, 16, 64); h.w += __shfl_xor(h.w, 32, 64);

    if (g == 0) {
        float rs = 1.0f / ss;
        bool has = end > beg;
        float4 o;
        o.x = has ? h.x * rs : 0.f;
        o.y = has ? h.y * rs : 0.f;
        o.z = has ? h.z * rs : 0.f;
        o.w = has ? h.w * rs : 0.f;
        o.x = (o.x > 0.f) ? o.x : (__expf(o.x) - 1.f);
        o.y = (o.y > 0.f) ? o.y : (__expf(o.y) - 1.f);
        o.z = (o.z > 0.f) ? o.z : (__expf(o.z) - 1.f);
        o.w = (o.w > 0.f) ? o.w : (__expf(o.w) - 1.f);
        *(float4*)&out[(size_t)node * F + i * 4] = o;
    }
}

extern "C" void kernel_launch(void* const* d_in, const int* in_sizes, int n_in,
                              void* d_out, int out_size, void* d_ws, size_t ws_size,
                              hipStream_t stream) {
    const float* m_sim = (const float*)d_in[0];
    const float* d_sim = (const float*)d_in[1];
    const float* Wm    = (const float*)d_in[2];
    const float* Wd    = (const float*)d_in[3];
    const int*   src   = (const int*)d_in[4];
    const int*   dst   = (const int*)d_in[5];
    int E = in_sizes[4];
    float* out = (float*)d_out;

    char* ws = (char*)d_ws;
    float* z      = (float*)ws; ws += (size_t)NN * F * 4;
    int*   deg    = (int*)ws;   ws += (size_t)NN * 4;
    int*   offs   = (int*)ws;   ws += (size_t)(NN + 1) * 4;
    int*   bsums  = (int*)ws;   ws += 128 * 4;
    int*   bcur   = (int*)ws;   ws += 512 * 4;
    int*   csr    = (int*)ws;   ws += (size_t)E * 4;
    int*   srcb_g = (int*)ws;   ws += (size_t)NBUCK * BCAP * 4;
    int*   dstb_g = (int*)ws;   ws += (size_t)NBUCK * BCAP * 4;

    hipMemsetAsync(bcur, 0, 512 * 4, stream);

    int nchunks = (E + CH - 1) / CH;
    bin_kernel<<<nchunks, 512, 0, stream>>>(src, dst, srcb_g, dstb_g, bcur, E);
    proj_kernel<<<NBP * 2, 256, 0, stream>>>(m_sim, d_sim, Wm, Wd, z);
    deg_kernel<<<NBUCK, 256, 0, stream>>>(dstb_g, bcur, deg);
    int nb = (NN + 1023) / 1024;   // 98
    scanA<<<nb, 256, 0, stream>>>(deg, offs + 1, bsums);
    scanB<<<1, 128, 0, stream>>>(bsums, nb);
    scanC<<<nb, 256, 0, stream>>>(offs, bsums);
    scatter2<<<NBUCK, 256, 0, stream>>>(srcb_g, dstb_g, bcur, offs, csr);
    gat_kernel<<<NN / 4, 256, 0, stream>>>(z, offs, csr, out);
}